// Round 1
// 57.868 us; speedup vs baseline: 1.0312x; 1.0312x over previous
//
#include <hip/hip_runtime.h>
#include <math.h>
#include <float.h>

#define OFFSET_X 1.0f
#define OFFSET_Y 0.3f
#define T_HORIZON 5.0f

__global__ __launch_bounds__(256) void BackupBarrierCBF_kernel(
    const float* __restrict__ data, float* __restrict__ out, int n)
{
    __shared__ float sdata[256 * 15];

    const int tid  = threadIdx.x;
    const int base = blockIdx.x * 256;
    const int i    = base + tid;

    // ---- coalesced stage: global -> LDS via float4 ----
    // block region = 256*15 floats = 15360 B, 16B-aligned (15360 % 16 == 0).
    const int nItems  = min(256, n - base);
    const int nFloats = nItems * 15;
    const float* gsrc = data + (size_t)base * 15;
    const int nVec4   = nFloats >> 2;
    const float4* src4 = reinterpret_cast<const float4*>(gsrc);
    float4* dst4       = reinterpret_cast<float4*>(sdata);
    for (int k = tid; k < nVec4; k += 256) dst4[k] = src4[k];
    for (int k = (nVec4 << 2) + tid; k < nFloats; k += 256) sdata[k] = gsrc[k];
    __syncthreads();

    if (i >= n) return;
    // stride-15 LDS read: 15 coprime with 32 banks -> 2-way aliasing (free)
    const float* p = sdata + tid * 15;

    const float ex0  = p[0],  ey0 = p[1],  eyaw = p[2],  ev = p[3];
    const float ax0  = p[4],  ay0 = p[5],  ayaw = p[6],  av = p[7];
    const float eL   = p[8],  eW  = p[9];
    const float aL   = p[11], aW  = p[12];
    const float dt   = p[14];

    const float nf = roundf(T_HORIZON / dt);   // n_t as float (50)

    float ce, se, ca, sa;
    sincosf(eyaw, &se, &ce);
    sincosf(ayaw, &sa, &ca);

    // Per-step relative displacement in ego frame (constant: yaw,v const).
    const float dvx = av * ca - ev * ce;
    const float dvy = av * sa - ev * se;
    const float dX  = ( dvx * ce + dvy * se) * dt;
    const float dY  = (-dvx * se + dvy * ce) * dt;

    const float rx0 = ax0 - ex0;
    const float ry0 = ay0 - ey0;

    const float hx  = 0.5f * eL + OFFSET_X;
    const float hy  = 0.5f * eW + OFFSET_Y;
    const float hcx = 0.5f * aL;
    const float hcy = 0.5f * aW;
    const float dh  = hx - hy;

    // Shared reciprocals for breakpoint candidates (inf/NaN handled by clamp).
    const float rX = __fdividef(1.0f, dX);
    const float rY = __fdividef(1.0f, dY);
    const float rP = __fdividef(1.0f, dX + dY);
    const float rM = __fdividef(1.0f, dX - dY);

    float m = FLT_MAX;

#pragma unroll
    for (int k = 0; k < 4; ++k) {
        const float cx = (k < 2)        ?  hcx : -hcx;
        const float cy = ((k & 1) == 0) ?  hcy : -hcy;
        const float wx = rx0 + cx * ca - cy * sa;
        const float wy = ry0 + cx * sa + cy * ca;
        const float X0 =  wx * ce + wy * se;   // corner pos in ego frame, t=0
        const float Y0 = -wx * se + wy * ce;

        // f(t) = max(|X0+t*dX|-hx, |Y0+t*dY|-hy) is convex piecewise-linear.
        // Continuous argmin t* lies at a breakpoint (or clamps to boundary):
        //   vertices of each |.| plus 4 branch crossings s1*u-hx == s2*v-hy.
        const float S = X0 + Y0;
        const float D = X0 - Y0;
        const float cands[6] = {
            -X0 * rX,          // vertex of |u|
            -Y0 * rY,          // vertex of |v|
            (dh - D) * rM,     // +u == +v
            (dh - S) * rP,     // +u == -v
            -(S + dh) * rP,    // -u == +v
            -(D + dh) * rM     // -u == -v
        };

#pragma unroll
        for (int c = 0; c < 6; ++c) {
            // clamp to [1, nf]; fmaxf(NaN,1)->1 makes 0/0 candidates safe
            const float tc = fminf(fmaxf(cands[c], 1.0f), nf);
            const float t0 = floorf(tc);
            const float t1 = fminf(t0 + 1.0f, nf);
            // convexity: integer argmin is floor(t*) or ceil(t*)
            const float d0 = fmaxf(fabsf(fmaf(t0, dX, X0)) - hx,
                                   fabsf(fmaf(t0, dY, Y0)) - hy);
            const float d1 = fmaxf(fabsf(fmaf(t1, dX, X0)) - hx,
                                   fabsf(fmaf(t1, dY, Y0)) - hy);
            m = fminf(m, fminf(d0, d1));
        }
    }

    const float s = 1.0f / (1.0f + expf(-m * 0.2f));
    out[i] = (s - 0.5f) * 10.0f;
}

extern "C" void kernel_launch(void* const* d_in, const int* in_sizes, int n_in,
                              void* d_out, int out_size, void* d_ws, size_t ws_size,
                              hipStream_t stream) {
    const float* data = (const float*)d_in[0];
    float* out = (float*)d_out;
    int n = out_size;  // B*A = 4096*32 = 131072
    int block = 256;
    int grid = (n + block - 1) / block;
    BackupBarrierCBF_kernel<<<grid, block, 0, stream>>>(data, out, n);
}